// Round 9
// baseline (260.265 us; speedup 1.0000x reference)
//
#include <hip/hip_runtime.h>
#include <hip/hip_bf16.h>
#include <math.h>
#include <stdint.h>

// Problem constants
#define BATCH 8
#define SEQ   2048
#define DMODEL 1024
#define GROUPS 2
#define VOCAB 320
#define NOUT  (GROUPS*VOCAB)   // 640
#define DG    (DMODEL/GROUPS)  // 512
#define NTOK  (BATCH*SEQ)      // 16384
#define NPAIR (NTOK*GROUPS)    // 32768
#define NCHUNK 10              // 64-col chunks per token

#define MARGIN 4.0f
#define NEG_INF (-3.0e38f)

typedef __attribute__((ext_vector_type(8))) short short8;
typedef __attribute__((ext_vector_type(8))) unsigned short ushort8;
typedef __attribute__((ext_vector_type(4))) float f32x4;

__device__ __forceinline__ unsigned short f2bf(float f) {
    __hip_bfloat16 h = __float2bfloat16(f);   // RNE
    return *reinterpret_cast<unsigned short*>(&h);
}
__device__ __forceinline__ float bf2f(unsigned short u) {
    unsigned int x = ((unsigned int)u) << 16;
    return __uint_as_float(x);
}

// async global->LDS 16B copy (wave-uniform base + lane*16 on the LDS side)
__device__ __forceinline__ void async16(const void* gptr, const void* lptr) {
    __builtin_amdgcn_global_load_lds(
        (const __attribute__((address_space(1))) unsigned int*)(unsigned long long)(uintptr_t)gptr,
        (__attribute__((address_space(3))) unsigned int*)(unsigned int)(uintptr_t)lptr,
        16, 0, 0);
}

// ---------------------------------------------------------------------------
// Kernel 1: fp32 -> bf16 conversion of X and W; block 0 zeroes hist + done.
// ---------------------------------------------------------------------------
#define NX4 (NTOK*DMODEL/4)    // 4194304
#define NW4 (NOUT*DMODEL/4)    // 163840
__global__ __launch_bounds__(256) void convert_kernel(
    const float* __restrict__ X, const float* __restrict__ W,
    unsigned short* __restrict__ Xb, unsigned short* __restrict__ Wb,
    int* __restrict__ hist, int* __restrict__ done)
{
    int i = blockIdx.x * 256 + threadIdx.x;
    if (blockIdx.x == 0) {
        for (int k = threadIdx.x; k < NOUT; k += 256) hist[k] = 0;
        if (threadIdx.x == 0) *done = 0;
    }
    const float4* src;
    ushort4* dst;
    int j;
    if (i < NX4) { src = (const float4*)X; dst = (ushort4*)Xb; j = i; }
    else         { src = (const float4*)W; dst = (ushort4*)Wb; j = i - NX4; if (j >= NW4) return; }
    float4 v = src[j];
    ushort4 u;
    u.x = f2bf(v.x); u.y = f2bf(v.y); u.z = f2bf(v.z); u.w = f2bf(v.w);
    dst[j] = u;
}

// ---------------------------------------------------------------------------
// Kernel 2: bf16 MFMA GEMM + fused per-(token,chunk) (max1,max2,argmax).
// Proven round-1 structure (global_load_lds -> sync -> MFMA -> sync), with
// BK=64: two 32-col sub-buffers staged per barrier pair -> 32 MFMA per
// drain instead of 16, halving the vmcnt(0)+barrier count (32 -> 16).
// LDS 32 KB (not occupancy-binding; grid-limited at 2.5 blocks/CU).
// ---------------------------------------------------------------------------
__global__ __launch_bounds__(256) void gemm_bf16_kernel(
    const unsigned short* __restrict__ Xb,   // [16384][1024]
    const unsigned short* __restrict__ Wb,   // [640][1024]
    const float* __restrict__ bias,          // [640]
    unsigned short* __restrict__ logits,     // [16384][640] bf16
    float* __restrict__ rec_m1,              // [NTOK][NCHUNK]
    float* __restrict__ rec_m2,              // [NTOK][NCHUNK]
    int*   __restrict__ rec_id)              // [NTOK][NCHUNK] (global col)
{
    __shared__ __align__(16) unsigned short As[2][128 * 32];  // 16 KB
    __shared__ __align__(16) unsigned short Bs[2][128 * 32];  // 16 KB

    const int tid  = threadIdx.x;
    const int lane = tid & 63;
    const int wave = tid >> 6;

    // XCD-chunked swizzle (640 = 8 XCDs x 80; measured neutral, harmless)
    const int bid  = blockIdx.x;
    const int wgid = (bid & 7) * 80 + (bid >> 3);
    const int m0 = (wgid / 5) * 128;
    const int n0 = (wgid % 5) * 128;

    const int wm = (wave & 1) * 64;
    const int wn = (wave >> 1) * 64;

    f32x4 acc[4][4];
    #pragma unroll
    for (int a = 0; a < 4; a++)
        #pragma unroll
        for (int b = 0; b < 4; b++)
            acc[a][b] = (f32x4)0.0f;

    int aoff[2], boff[2], loff[2];
    #pragma unroll
    for (int j = 0; j < 2; j++) {
        int p = tid + j * 256;
        int r = p >> 2, s = p & 3;
        int c = s ^ ((r >> 1) & 3);
        aoff[j] = (m0 + r) * DMODEL + c * 8;
        boff[j] = (n0 + r) * DMODEL + c * 8;
        loff[j] = p * 8;
    }

    int afrag[4], bfrag[4];
    {
        int rho = lane & 15, h = lane >> 4;
        #pragma unroll
        for (int mi = 0; mi < 4; mi++) {
            int r = wm + mi * 16 + rho;
            afrag[mi] = (4 * r + (h ^ ((r >> 1) & 3))) * 8;
            int rn = wn + mi * 16 + rho;
            bfrag[mi] = (4 * rn + (h ^ ((rn >> 1) & 3))) * 8;
        }
    }

    for (int k0 = 0; k0 < DMODEL; k0 += 64) {
        #pragma unroll
        for (int h = 0; h < 2; h++)
            #pragma unroll
            for (int j = 0; j < 2; j++) {
                async16(Xb + aoff[j] + k0 + h * 32, As[h] + loff[j]);
                async16(Wb + boff[j] + k0 + h * 32, Bs[h] + loff[j]);
            }
        __syncthreads();

        #pragma unroll
        for (int h = 0; h < 2; h++) {
            short8 af[4], bf[4];
            #pragma unroll
            for (int i = 0; i < 4; i++) {
                af[i] = *(const short8*)&As[h][afrag[i]];
                bf[i] = *(const short8*)&Bs[h][bfrag[i]];
            }
            #pragma unroll
            for (int mi = 0; mi < 4; mi++)
                #pragma unroll
                for (int ni = 0; ni < 4; ni++)
                    acc[mi][ni] = __builtin_amdgcn_mfma_f32_16x16x32_bf16(
                        af[mi], bf[ni], acc[mi][ni], 0, 0, 0);
        }
        __syncthreads();
    }

    // Epilogue: bias add, bf16 logit store, per-row (64-col) max1/max2/idx
    const int colb = n0 + wn + (lane & 15);
    const int rowb = m0 + wm + (lane >> 4) * 4;
    const int chunk = (n0 + wn) >> 6;   // 0..9
    float bv[4];
    #pragma unroll
    for (int ni = 0; ni < 4; ni++) bv[ni] = bias[colb + ni * 16];

    #pragma unroll
    for (int mi = 0; mi < 4; mi++) {
        #pragma unroll
        for (int p = 0; p < 4; p++) {
            const int row = rowb + mi * 16 + p;
            // local max over this lane's 4 cols (ascending col order)
            float m1 = acc[mi][0][p] + bv[0];
            float m2 = NEG_INF;
            int i1 = colb;
            logits[row * NOUT + colb] = f2bf(m1);
            #pragma unroll
            for (int ni = 1; ni < 4; ni++) {
                float v = acc[mi][ni][p] + bv[ni];
                logits[row * NOUT + colb + ni * 16] = f2bf(v);
                if (v > m1) { m2 = m1; m1 = v; i1 = colb + ni * 16; }
                else        { m2 = fmaxf(m2, v); }
            }
            // reduce across the 16 lanes of this row group (xor 1,2,4,8)
            #pragma unroll
            for (int off = 1; off < 16; off <<= 1) {
                float om1 = __shfl_xor(m1, off);
                float om2 = __shfl_xor(m2, off);
                int   oi  = __shfl_xor(i1, off);
                float nm2 = fmaxf(fmaxf(m2, om2), fminf(m1, om1));
                if (om1 > m1 || (om1 == m1 && oi < i1)) { m1 = om1; i1 = oi; }
                m2 = nm2;
            }
            if ((lane & 15) == 0) {
                rec_m1[row * NCHUNK + chunk] = m1;
                rec_m2[row * NCHUNK + chunk] = m2;
                rec_id[row * NCHUNK + chunk] = i1;
            }
        }
    }
}

// ---------------------------------------------------------------------------
// Kernel 3: FUSED reduce + resolve + gather + diversity. 512 blocks; block b
// owns pairs [b*64, b*64+64) == tokens [b*32, b*32+32).
//   phase 1 (wave 0): per-pair chunk reduce; ambiguous -> LDS list (ballot);
//                     unambiguous -> hist atomicAdd (device-scope)
//   phase 2 (4 waves): wave-per-slot bf16 scan + exact fp32 rescore; lane 0
//                      writes out_idx + hist atomicAdd
//   [fence + done-counter BEFORE the bulk gather -> cheap, unlike r3]
//   phase 3 (256 thr): gather the 32 token rows from the codebook
//   phase 4 (last block only): diversity scalar from hist (atomic reads)
// ---------------------------------------------------------------------------
__global__ __launch_bounds__(256) void finalize_kernel(
    const float* __restrict__ X, const float* __restrict__ W,
    const float* __restrict__ bias,
    const unsigned short* __restrict__ logits,
    const float* __restrict__ rec_m1, const float* __restrict__ rec_m2,
    const int* __restrict__ rec_id,
    const float* __restrict__ cb,
    float* __restrict__ out, float* __restrict__ out_idx,
    int* __restrict__ hist, int* __restrict__ done,
    float* __restrict__ out_loss)
{
    __shared__ int   lcol[64];    // global codebook row per local pair
    __shared__ float lM[64];      // chunk-max for ambiguous pairs
    __shared__ int   lamb[64];    // compacted local indices of ambiguous pairs
    __shared__ int   slcnt;
    __shared__ int   lastFlag;
    __shared__ float s0[256], s1[256];

    const int tid   = threadIdx.x;
    const int lane  = tid & 63;
    const int wave  = tid >> 6;
    const int pair0 = blockIdx.x * 64;

    // ---- phase 1: reduce (wave 0 only; lane == local pair index) ----
    if (tid < 64) {
        const int pair  = pair0 + tid;
        const int token = pair >> 1;
        const int g     = pair & 1;
        const int base  = token * NCHUNK + g * 5;

        float m1[5], M;
        int cstar = 0;
        #pragma unroll
        for (int c = 0; c < 5; c++) m1[c] = rec_m1[base + c];
        M = m1[0];
        #pragma unroll
        for (int c = 1; c < 5; c++)
            if (m1[c] > M) { M = m1[c]; cstar = c; }
        const float m2s = rec_m2[base + cstar];

        const float thr = M - MARGIN;
        bool amb = (m2s >= thr);
        #pragma unroll
        for (int c = 0; c < 5; c++)
            if (c != cstar && m1[c] >= thr) amb = true;

        if (!amb) {
            const int gcol = rec_id[base + cstar];       // global col
            lcol[tid] = gcol;
            out_idx[pair] = (float)(gcol - g * VOCAB);
            atomicAdd(&hist[gcol], 1);
        } else {
            lM[tid] = M;
        }
        unsigned long long mask = __ballot(amb);
        if (amb) {
            int off = __popcll(mask & ((1ull << tid) - 1ull));
            lamb[off] = tid;
        }
        if (tid == 0) slcnt = (int)__popcll(mask);
    }
    __syncthreads();
    const int nloc = slcnt;

    // ---- phase 2: resolve ambiguous (wave-per-slot over LDS list) ----
    for (int s = wave; s < nloc; s += 4) {
        const int lp    = lamb[s];
        const int pair  = pair0 + lp;
        const float M   = lM[lp];
        const int token = pair >> 1;
        const int g     = pair & 1;

        // cache this token's X row: 16 floats per lane
        const float4* xr = (const float4*)(X + (size_t)token * DMODEL);
        float4 xv[4];
        #pragma unroll
        for (int q = 0; q < 4; q++) xv[q] = xr[lane + 64 * q];

        // load this pair's bf16 logit row (40 lanes x 8 values = 320)
        const unsigned short* lp_ = logits + token * NOUT + g * VOCAB;
        const bool have = (lane < 40);
        ushort8 u = (ushort8)0;
        if (have) u = *(const ushort8*)(lp_ + lane * 8);

        const float thr = M - MARGIN;
        float best = NEG_INF;
        int bestcol = 0;

        #pragma unroll
        for (int j = 0; j < 8; j++) {
            bool c = have && (bf2f(u[j]) >= thr);
            unsigned long long mask = __ballot(c);   // wave-uniform
            while (mask) {
                const int b = __ffsll((long long)mask) - 1;
                mask &= mask - 1;
                const int col = b * 8 + j;           // 0..319
                const float4* wr = (const float4*)(W + (size_t)(g * VOCAB + col) * DMODEL);
                float acc = 0.0f;
                #pragma unroll
                for (int q = 0; q < 4; q++) {
                    float4 bb = wr[lane + 64 * q];
                    acc = fmaf(xv[q].x, bb.x, acc);
                    acc = fmaf(xv[q].y, bb.y, acc);
                    acc = fmaf(xv[q].z, bb.z, acc);
                    acc = fmaf(xv[q].w, bb.w, acc);
                }
                #pragma unroll
                for (int off = 32; off >= 1; off >>= 1)
                    acc += __shfl_xor(acc, off);
                const float logit = acc + bias[g * VOCAB + col];
                if (logit > best || (logit == best && col < bestcol)) {
                    best = logit; bestcol = col;
                }
            }
        }
        if (lane == 0) {
            const int gcol = g * VOCAB + bestcol;
            lcol[lp] = gcol;
            out_idx[pair] = (float)bestcol;
            atomicAdd(&hist[gcol], 1);
        }
    }

    // ---- fence + done-counter BEFORE the bulk gather stores.
    // Only ~300 B of stores + 64 atomics precede it -> cheap (r3's mistake
    // was fencing AFTER 64 KB of gather stores per block).
    __threadfence();
    __syncthreads();
    if (tid == 0) lastFlag = (atomicAdd(done, 1) == (int)gridDim.x - 1);
    __syncthreads();

    // ---- phase 3: gather 32 tokens x 1024 floats (one row per iter) ----
    #pragma unroll 4
    for (int i = 0; i < 32; i++) {
        const int token = pair0 / 2 + i;
        const int gg = tid >> 7;
        const float4* src = (const float4*)(cb + (size_t)lcol[i * 2 + gg] * DG);
        ((float4*)(out + (size_t)token * DMODEL))[tid] = src[tid & 127];
    }

    // ---- phase 4: last block computes diversity from hist ----
    if (!lastFlag) return;

    float a0 = 0.0f, a1 = 0.0f;
    for (int i = tid; i < NOUT; i += 256) {
        int h = atomicAdd(&hist[i], 0);      // device-scope coherent read
        float m = (float)h * (1.0f / (float)NTOK);
        float t = m * logf(m + 1e-7f);
        if (i < VOCAB) a0 += t; else a1 += t;
    }
    s0[tid] = a0; s1[tid] = a1;
    __syncthreads();
    for (int s = 128; s > 0; s >>= 1) {
        if (tid < s) { s0[tid] += s0[tid + s]; s1[tid] += s1[tid + s]; }
        __syncthreads();
    }
    if (tid == 0) {
        float perplexity = expf(-s0[0]) + expf(-s1[0]);
        *out_loss = ((float)NOUT - perplexity) / (float)NOUT * 0.1f;
    }
}

// ---------------------------------------------------------------------------
extern "C" void kernel_launch(void* const* d_in, const int* in_sizes, int n_in,
                              void* d_out, int out_size, void* d_ws, size_t ws_size,
                              hipStream_t stream) {
    const float* X    = (const float*)d_in[0];
    const float* W    = (const float*)d_in[1];
    const float* bias = (const float*)d_in[2];
    const float* cb   = (const float*)d_in[3];

    float* out      = (float*)d_out;
    float* out_idx  = out + (size_t)NTOK * DMODEL;
    float* out_loss = out_idx + NPAIR;

    // workspace layout
    char* p = (char*)d_ws;
    unsigned short* Xb = (unsigned short*)p;      p += (size_t)NTOK * DMODEL * 2;   // 32 MB
    unsigned short* Wb = (unsigned short*)p;      p += (size_t)NOUT * DMODEL * 2;   // 1.25 MB
    unsigned short* logits = (unsigned short*)p;  p += (size_t)NTOK * NOUT * 2;     // 20 MB
    float* rec_m1 = (float*)p;                    p += (size_t)NTOK * NCHUNK * 4;   // 640 KB
    float* rec_m2 = (float*)p;                    p += (size_t)NTOK * NCHUNK * 4;
    int*   rec_id = (int*)p;                      p += (size_t)NTOK * NCHUNK * 4;
    int* hist = (int*)p;                          p += NOUT * 4;
    int* done = (int*)p;                          p += 256;

    convert_kernel<<<(NX4 + NW4) / 256, 256, 0, stream>>>(X, W, Xb, Wb,
                                                          hist, done);

    // 1-D grid, XCD-chunked swizzle inside the kernel (640 = 8 XCDs x 80)
    gemm_bf16_kernel<<<640, 256, 0, stream>>>(Xb, Wb, bias, logits,
                                              rec_m1, rec_m2, rec_id);

    finalize_kernel<<<NPAIR / 64, 256, 0, stream>>>(X, W, bias, logits,
                                                    rec_m1, rec_m2, rec_id,
                                                    cb, out, out_idx,
                                                    hist, done, out_loss);
}

// Round 10
// 195.568 us; speedup vs baseline: 1.3308x; 1.3308x over previous
//
#include <hip/hip_runtime.h>
#include <hip/hip_bf16.h>
#include <math.h>
#include <stdint.h>

// Problem constants
#define BATCH 8
#define SEQ   2048
#define DMODEL 1024
#define GROUPS 2
#define VOCAB 320
#define NOUT  (GROUPS*VOCAB)   // 640
#define DG    (DMODEL/GROUPS)  // 512
#define NTOK  (BATCH*SEQ)      // 16384
#define NPAIR (NTOK*GROUPS)    // 32768
#define NCHUNK 10              // 64-col chunks per token

#define MARGIN 4.0f
#define NEG_INF (-3.0e38f)

typedef __attribute__((ext_vector_type(8))) short short8;
typedef __attribute__((ext_vector_type(8))) unsigned short ushort8;
typedef __attribute__((ext_vector_type(4))) float f32x4;

__device__ __forceinline__ unsigned short f2bf(float f) {
    __hip_bfloat16 h = __float2bfloat16(f);   // RNE
    return *reinterpret_cast<unsigned short*>(&h);
}
__device__ __forceinline__ float bf2f(unsigned short u) {
    unsigned int x = ((unsigned int)u) << 16;
    return __uint_as_float(x);
}

// async global->LDS 16B copy (wave-uniform base + lane*16 on the LDS side)
__device__ __forceinline__ void async16(const void* gptr, const void* lptr) {
    __builtin_amdgcn_global_load_lds(
        (const __attribute__((address_space(1))) unsigned int*)(unsigned long long)(uintptr_t)gptr,
        (__attribute__((address_space(3))) unsigned int*)(unsigned int)(uintptr_t)lptr,
        16, 0, 0);
}

// ---------------------------------------------------------------------------
// Kernel 1: fp32 -> bf16 conversion of X and W   (proven)
// ---------------------------------------------------------------------------
#define NX4 (NTOK*DMODEL/4)    // 4194304
#define NW4 (NOUT*DMODEL/4)    // 163840
__global__ __launch_bounds__(256) void convert_kernel(
    const float* __restrict__ X, const float* __restrict__ W,
    unsigned short* __restrict__ Xb, unsigned short* __restrict__ Wb)
{
    int i = blockIdx.x * 256 + threadIdx.x;
    const float4* src;
    ushort4* dst;
    int j;
    if (i < NX4) { src = (const float4*)X; dst = (ushort4*)Xb; j = i; }
    else         { src = (const float4*)W; dst = (ushort4*)Wb; j = i - NX4; if (j >= NW4) return; }
    float4 v = src[j];
    ushort4 u;
    u.x = f2bf(v.x); u.y = f2bf(v.y); u.z = f2bf(v.z); u.w = f2bf(v.w);
    dst[j] = u;
}

// ---------------------------------------------------------------------------
// Kernel 2: bf16 MFMA GEMM + fused per-(token,chunk) (max1,max2,argmax).
// Round-1 structure with BK=64: two 32-col sub-buffers staged per barrier
// pair -> 32 MFMA per vmcnt(0)+barrier drain instead of 16 (drain count
// 32 -> 16). LDS 32 KB — not occupancy-binding (grid-limited 2.5 blk/CU).
// THIS ROUND measures BK=64 in isolation vs the 45.4 us BK=32 baseline.
// ---------------------------------------------------------------------------
__global__ __launch_bounds__(256) void gemm_bf16_kernel(
    const unsigned short* __restrict__ Xb,   // [16384][1024]
    const unsigned short* __restrict__ Wb,   // [640][1024]
    const float* __restrict__ bias,          // [640]
    unsigned short* __restrict__ logits,     // [16384][640] bf16
    float* __restrict__ rec_m1,              // [NTOK][NCHUNK]
    float* __restrict__ rec_m2,              // [NTOK][NCHUNK]
    int*   __restrict__ rec_id)              // [NTOK][NCHUNK] (global col)
{
    __shared__ __align__(16) unsigned short As[2][128 * 32];  // 16 KB
    __shared__ __align__(16) unsigned short Bs[2][128 * 32];  // 16 KB

    const int tid  = threadIdx.x;
    const int lane = tid & 63;
    const int wave = tid >> 6;

    // XCD-chunked swizzle (640 = 8 XCDs x 80; measured neutral, harmless)
    const int bid  = blockIdx.x;
    const int wgid = (bid & 7) * 80 + (bid >> 3);
    const int m0 = (wgid / 5) * 128;
    const int n0 = (wgid % 5) * 128;

    const int wm = (wave & 1) * 64;
    const int wn = (wave >> 1) * 64;

    f32x4 acc[4][4];
    #pragma unroll
    for (int a = 0; a < 4; a++)
        #pragma unroll
        for (int b = 0; b < 4; b++)
            acc[a][b] = (f32x4)0.0f;

    int aoff[2], boff[2], loff[2];
    #pragma unroll
    for (int j = 0; j < 2; j++) {
        int p = tid + j * 256;
        int r = p >> 2, s = p & 3;
        int c = s ^ ((r >> 1) & 3);
        aoff[j] = (m0 + r) * DMODEL + c * 8;
        boff[j] = (n0 + r) * DMODEL + c * 8;
        loff[j] = p * 8;
    }

    int afrag[4], bfrag[4];
    {
        int rho = lane & 15, h = lane >> 4;
        #pragma unroll
        for (int mi = 0; mi < 4; mi++) {
            int r = wm + mi * 16 + rho;
            afrag[mi] = (4 * r + (h ^ ((r >> 1) & 3))) * 8;
            int rn = wn + mi * 16 + rho;
            bfrag[mi] = (4 * rn + (h ^ ((rn >> 1) & 3))) * 8;
        }
    }

    for (int k0 = 0; k0 < DMODEL; k0 += 64) {
        #pragma unroll
        for (int h = 0; h < 2; h++)
            #pragma unroll
            for (int j = 0; j < 2; j++) {
                async16(Xb + aoff[j] + k0 + h * 32, As[h] + loff[j]);
                async16(Wb + boff[j] + k0 + h * 32, Bs[h] + loff[j]);
            }
        __syncthreads();

        #pragma unroll
        for (int h = 0; h < 2; h++) {
            short8 af[4], bf[4];
            #pragma unroll
            for (int i = 0; i < 4; i++) {
                af[i] = *(const short8*)&As[h][afrag[i]];
                bf[i] = *(const short8*)&Bs[h][bfrag[i]];
            }
            #pragma unroll
            for (int mi = 0; mi < 4; mi++)
                #pragma unroll
                for (int ni = 0; ni < 4; ni++)
                    acc[mi][ni] = __builtin_amdgcn_mfma_f32_16x16x32_bf16(
                        af[mi], bf[ni], acc[mi][ni], 0, 0, 0);
        }
        __syncthreads();
    }

    // Epilogue: bias add, bf16 logit store, per-row (64-col) max1/max2/idx
    const int colb = n0 + wn + (lane & 15);
    const int rowb = m0 + wm + (lane >> 4) * 4;
    const int chunk = (n0 + wn) >> 6;   // 0..9
    float bv[4];
    #pragma unroll
    for (int ni = 0; ni < 4; ni++) bv[ni] = bias[colb + ni * 16];

    #pragma unroll
    for (int mi = 0; mi < 4; mi++) {
        #pragma unroll
        for (int p = 0; p < 4; p++) {
            const int row = rowb + mi * 16 + p;
            // local max over this lane's 4 cols (ascending col order)
            float m1 = acc[mi][0][p] + bv[0];
            float m2 = NEG_INF;
            int i1 = colb;
            logits[row * NOUT + colb] = f2bf(m1);
            #pragma unroll
            for (int ni = 1; ni < 4; ni++) {
                float v = acc[mi][ni][p] + bv[ni];
                logits[row * NOUT + colb + ni * 16] = f2bf(v);
                if (v > m1) { m2 = m1; m1 = v; i1 = colb + ni * 16; }
                else        { m2 = fmaxf(m2, v); }
            }
            // reduce across the 16 lanes of this row group (xor 1,2,4,8)
            #pragma unroll
            for (int off = 1; off < 16; off <<= 1) {
                float om1 = __shfl_xor(m1, off);
                float om2 = __shfl_xor(m2, off);
                int   oi  = __shfl_xor(i1, off);
                float nm2 = fmaxf(fmaxf(m2, om2), fminf(m1, om1));
                if (om1 > m1 || (om1 == m1 && oi < i1)) { m1 = om1; i1 = oi; }
                m2 = nm2;
            }
            if ((lane & 15) == 0) {
                rec_m1[row * NCHUNK + chunk] = m1;
                rec_m2[row * NCHUNK + chunk] = m2;
                rec_id[row * NCHUNK + chunk] = i1;
            }
        }
    }
}

// ---------------------------------------------------------------------------
// Kernel 3: FUSED reduce + resolve + gather (proven round-6 form: NO hist,
// NO fence, NO done counter — per-block device-scope fences are catastrophic
// on gfx950: they invalidate L2 and turn the cb gather into re-fetch storms,
// measured twice: r3 +130 us, r9 +90 us).
// 512 blocks; block b owns pairs [b*64, b*64+64) == tokens [b*32, b*32+32).
// ---------------------------------------------------------------------------
__global__ __launch_bounds__(256) void finalize_kernel(
    const float* __restrict__ X, const float* __restrict__ W,
    const float* __restrict__ bias,
    const unsigned short* __restrict__ logits,
    const float* __restrict__ rec_m1, const float* __restrict__ rec_m2,
    const int* __restrict__ rec_id,
    const float* __restrict__ cb,
    float* __restrict__ out, float* __restrict__ out_idx)
{
    __shared__ int   lcol[64];    // global codebook row per local pair
    __shared__ float lM[64];      // chunk-max for ambiguous pairs
    __shared__ int   lamb[64];    // compacted local indices of ambiguous pairs
    __shared__ int   slcnt;

    const int tid   = threadIdx.x;
    const int lane  = tid & 63;
    const int wave  = tid >> 6;
    const int pair0 = blockIdx.x * 64;

    // ---- phase 1: reduce (wave 0 only; lane == local pair index) ----
    if (tid < 64) {
        const int pair  = pair0 + tid;
        const int token = pair >> 1;
        const int g     = pair & 1;
        const int base  = token * NCHUNK + g * 5;

        float m1[5], M;
        int cstar = 0;
        #pragma unroll
        for (int c = 0; c < 5; c++) m1[c] = rec_m1[base + c];
        M = m1[0];
        #pragma unroll
        for (int c = 1; c < 5; c++)
            if (m1[c] > M) { M = m1[c]; cstar = c; }
        const float m2s = rec_m2[base + cstar];

        const float thr = M - MARGIN;
        bool amb = (m2s >= thr);
        #pragma unroll
        for (int c = 0; c < 5; c++)
            if (c != cstar && m1[c] >= thr) amb = true;

        if (!amb) {
            const int gcol = rec_id[base + cstar];       // global col
            lcol[tid] = gcol;
            out_idx[pair] = (float)(gcol - g * VOCAB);
        } else {
            lM[tid] = M;
        }
        unsigned long long mask = __ballot(amb);
        if (amb) {
            int off = __popcll(mask & ((1ull << tid) - 1ull));
            lamb[off] = tid;
        }
        if (tid == 0) slcnt = (int)__popcll(mask);
    }
    __syncthreads();
    const int nloc = slcnt;

    // ---- phase 2: resolve ambiguous (wave-per-slot over LDS list) ----
    for (int s = wave; s < nloc; s += 4) {
        const int lp    = lamb[s];
        const int pair  = pair0 + lp;
        const float M   = lM[lp];
        const int token = pair >> 1;
        const int g     = pair & 1;

        // cache this token's X row: 16 floats per lane
        const float4* xr = (const float4*)(X + (size_t)token * DMODEL);
        float4 xv[4];
        #pragma unroll
        for (int q = 0; q < 4; q++) xv[q] = xr[lane + 64 * q];

        // load this pair's bf16 logit row (40 lanes x 8 values = 320)
        const unsigned short* lp_ = logits + token * NOUT + g * VOCAB;
        const bool have = (lane < 40);
        ushort8 u = (ushort8)0;
        if (have) u = *(const ushort8*)(lp_ + lane * 8);

        const float thr = M - MARGIN;
        float best = NEG_INF;
        int bestcol = 0;

        #pragma unroll
        for (int j = 0; j < 8; j++) {
            bool c = have && (bf2f(u[j]) >= thr);
            unsigned long long mask = __ballot(c);   // wave-uniform
            while (mask) {
                const int b = __ffsll((long long)mask) - 1;
                mask &= mask - 1;
                const int col = b * 8 + j;           // 0..319
                const float4* wr = (const float4*)(W + (size_t)(g * VOCAB + col) * DMODEL);
                float acc = 0.0f;
                #pragma unroll
                for (int q = 0; q < 4; q++) {
                    float4 bb = wr[lane + 64 * q];
                    acc = fmaf(xv[q].x, bb.x, acc);
                    acc = fmaf(xv[q].y, bb.y, acc);
                    acc = fmaf(xv[q].z, bb.z, acc);
                    acc = fmaf(xv[q].w, bb.w, acc);
                }
                #pragma unroll
                for (int off = 32; off >= 1; off >>= 1)
                    acc += __shfl_xor(acc, off);
                const float logit = acc + bias[g * VOCAB + col];
                if (logit > best || (logit == best && col < bestcol)) {
                    best = logit; bestcol = col;
                }
            }
        }
        if (lane == 0) {
            lcol[lp] = g * VOCAB + bestcol;
            out_idx[pair] = (float)bestcol;
        }
    }
    __syncthreads();

    // ---- phase 3: gather 32 tokens x 1024 floats (one row per iter) ----
    #pragma unroll 4
    for (int i = 0; i < 32; i++) {
        const int token = pair0 / 2 + i;
        const int gg = tid >> 7;
        const float4* src = (const float4*)(cb + (size_t)lcol[i * 2 + gg] * DG);
        ((float4*)(out + (size_t)token * DMODEL))[tid] = src[tid & 127];
    }
}

// ---------------------------------------------------------------------------
// Kernel 4: diversity loss — single block builds the histogram from out_idx
// in LDS (LDS atomics) and computes the scalar. 128 KB read, trivial.
// ---------------------------------------------------------------------------
__global__ __launch_bounds__(256) void diversity_kernel(
    const float* __restrict__ out_idx, float* __restrict__ out_scalar)
{
    __shared__ int lhist[NOUT];
    __shared__ float s0[256], s1[256];
    const int tid = threadIdx.x;
    for (int i = tid; i < NOUT; i += 256) lhist[i] = 0;
    __syncthreads();

    // NPAIR = 32768 floats; read as float4 (pairs 4i..4i+3, g = pair&1)
    const float4* oi4 = (const float4*)out_idx;
    for (int i = tid; i < NPAIR / 4; i += 256) {
        float4 v = oi4[i];
        atomicAdd(&lhist[0 * VOCAB + (int)v.x], 1);   // pair 4i   : g=0
        atomicAdd(&lhist[1 * VOCAB + (int)v.y], 1);   // pair 4i+1 : g=1
        atomicAdd(&lhist[0 * VOCAB + (int)v.z], 1);   // pair 4i+2 : g=0
        atomicAdd(&lhist[1 * VOCAB + (int)v.w], 1);   // pair 4i+3 : g=1
    }
    __syncthreads();

    float a0 = 0.0f, a1 = 0.0f;
    for (int i = tid; i < NOUT; i += 256) {
        float m = (float)lhist[i] * (1.0f / (float)NTOK);
        float t = m * logf(m + 1e-7f);
        if (i < VOCAB) a0 += t; else a1 += t;
    }
    s0[tid] = a0; s1[tid] = a1;
    __syncthreads();
    for (int s = 128; s > 0; s >>= 1) {
        if (tid < s) { s0[tid] += s0[tid + s]; s1[tid] += s1[tid + s]; }
        __syncthreads();
    }
    if (tid == 0) {
        float perplexity = expf(-s0[0]) + expf(-s1[0]);
        *out_scalar = ((float)NOUT - perplexity) / (float)NOUT * 0.1f;
    }
}

// ---------------------------------------------------------------------------
extern "C" void kernel_launch(void* const* d_in, const int* in_sizes, int n_in,
                              void* d_out, int out_size, void* d_ws, size_t ws_size,
                              hipStream_t stream) {
    const float* X    = (const float*)d_in[0];
    const float* W    = (const float*)d_in[1];
    const float* bias = (const float*)d_in[2];
    const float* cb   = (const float*)d_in[3];

    float* out      = (float*)d_out;
    float* out_idx  = out + (size_t)NTOK * DMODEL;
    float* out_loss = out_idx + NPAIR;

    // workspace layout
    char* p = (char*)d_ws;
    unsigned short* Xb = (unsigned short*)p;      p += (size_t)NTOK * DMODEL * 2;   // 32 MB
    unsigned short* Wb = (unsigned short*)p;      p += (size_t)NOUT * DMODEL * 2;   // 1.25 MB
    unsigned short* logits = (unsigned short*)p;  p += (size_t)NTOK * NOUT * 2;     // 20 MB
    float* rec_m1 = (float*)p;                    p += (size_t)NTOK * NCHUNK * 4;   // 640 KB
    float* rec_m2 = (float*)p;                    p += (size_t)NTOK * NCHUNK * 4;
    int*   rec_id = (int*)p;                      p += (size_t)NTOK * NCHUNK * 4;

    convert_kernel<<<(NX4 + NW4) / 256, 256, 0, stream>>>(X, W, Xb, Wb);

    // 1-D grid, XCD-chunked swizzle inside the kernel (640 = 8 XCDs x 80)
    gemm_bf16_kernel<<<640, 256, 0, stream>>>(Xb, Wb, bias, logits,
                                              rec_m1, rec_m2, rec_id);

    finalize_kernel<<<NPAIR / 64, 256, 0, stream>>>(X, W, bias, logits,
                                                    rec_m1, rec_m2, rec_id,
                                                    cb, out, out_idx);

    diversity_kernel<<<1, 256, 0, stream>>>(out_idx, out_loss);
}

// Round 11
// 190.190 us; speedup vs baseline: 1.3684x; 1.0283x over previous
//
#include <hip/hip_runtime.h>
#include <hip/hip_bf16.h>
#include <math.h>
#include <stdint.h>

// Problem constants
#define BATCH 8
#define SEQ   2048
#define DMODEL 1024
#define GROUPS 2
#define VOCAB 320
#define NOUT  (GROUPS*VOCAB)   // 640
#define DG    (DMODEL/GROUPS)  // 512
#define NTOK  (BATCH*SEQ)      // 16384
#define NPAIR (NTOK*GROUPS)    // 32768
#define NCHUNK 10              // 64-col chunks per token

#define MARGIN 4.0f
#define NEG_INF (-3.0e38f)

typedef __attribute__((ext_vector_type(8))) short short8;
typedef __attribute__((ext_vector_type(8))) unsigned short ushort8;
typedef __attribute__((ext_vector_type(4))) float f32x4;

__device__ __forceinline__ unsigned short f2bf(float f) {
    __hip_bfloat16 h = __float2bfloat16(f);   // RNE
    return *reinterpret_cast<unsigned short*>(&h);
}
__device__ __forceinline__ float bf2f(unsigned short u) {
    unsigned int x = ((unsigned int)u) << 16;
    return __uint_as_float(x);
}

// async global->LDS 16B copy (wave-uniform base + lane*16 on the LDS side)
__device__ __forceinline__ void async16(const void* gptr, const void* lptr) {
    __builtin_amdgcn_global_load_lds(
        (const __attribute__((address_space(1))) unsigned int*)(unsigned long long)(uintptr_t)gptr,
        (__attribute__((address_space(3))) unsigned int*)(unsigned int)(uintptr_t)lptr,
        16, 0, 0);
}

// ---------------------------------------------------------------------------
// Kernel 1: fp32 -> bf16 conversion of X and W.
// G13 fix: 8 floats/thread — 2x float4 loads (32 B/lane) + 1x ushort8 store
// (16 B/lane, coalescing sweet spot). Was ushort4 = 8 B/lane stores.
// ---------------------------------------------------------------------------
#define NX8 (NTOK*DMODEL/8)    // 2097152
#define NW8 (NOUT*DMODEL/8)    // 81920
__global__ __launch_bounds__(256) void convert_kernel(
    const float* __restrict__ X, const float* __restrict__ W,
    unsigned short* __restrict__ Xb, unsigned short* __restrict__ Wb)
{
    int i = blockIdx.x * 256 + threadIdx.x;
    const float4* src;
    ushort8* dst;
    int j;
    if (i < NX8) { src = (const float4*)X; dst = (ushort8*)Xb; j = i; }
    else         { src = (const float4*)W; dst = (ushort8*)Wb; j = i - NX8; if (j >= NW8) return; }
    float4 v0 = src[j * 2], v1 = src[j * 2 + 1];
    ushort8 u;
    u[0] = f2bf(v0.x); u[1] = f2bf(v0.y); u[2] = f2bf(v0.z); u[3] = f2bf(v0.w);
    u[4] = f2bf(v1.x); u[5] = f2bf(v1.y); u[6] = f2bf(v1.z); u[7] = f2bf(v1.w);
    dst[j] = u;
}

// ---------------------------------------------------------------------------
// Kernel 2: bf16 MFMA GEMM + fused per-(token,chunk) (max1,max2,argmax).
// Structural floor (~43.5 us) declared after r2/r3/r6/r8/r10 attempts.
// BK=64: 32 MFMA per vmcnt(0)+barrier drain; LDS 32 KB (grid-limited
// occupancy 2.5 blk/CU, not LDS-limited).
// ---------------------------------------------------------------------------
__global__ __launch_bounds__(256) void gemm_bf16_kernel(
    const unsigned short* __restrict__ Xb,   // [16384][1024]
    const unsigned short* __restrict__ Wb,   // [640][1024]
    const float* __restrict__ bias,          // [640]
    unsigned short* __restrict__ logits,     // [16384][640] bf16
    float* __restrict__ rec_m1,              // [NTOK][NCHUNK]
    float* __restrict__ rec_m2,              // [NTOK][NCHUNK]
    int*   __restrict__ rec_id)              // [NTOK][NCHUNK] (global col)
{
    __shared__ __align__(16) unsigned short As[2][128 * 32];  // 16 KB
    __shared__ __align__(16) unsigned short Bs[2][128 * 32];  // 16 KB

    const int tid  = threadIdx.x;
    const int lane = tid & 63;
    const int wave = tid >> 6;

    // XCD-chunked swizzle (640 = 8 XCDs x 80; measured neutral, harmless)
    const int bid  = blockIdx.x;
    const int wgid = (bid & 7) * 80 + (bid >> 3);
    const int m0 = (wgid / 5) * 128;
    const int n0 = (wgid % 5) * 128;

    const int wm = (wave & 1) * 64;
    const int wn = (wave >> 1) * 64;

    f32x4 acc[4][4];
    #pragma unroll
    for (int a = 0; a < 4; a++)
        #pragma unroll
        for (int b = 0; b < 4; b++)
            acc[a][b] = (f32x4)0.0f;

    int aoff[2], boff[2], loff[2];
    #pragma unroll
    for (int j = 0; j < 2; j++) {
        int p = tid + j * 256;
        int r = p >> 2, s = p & 3;
        int c = s ^ ((r >> 1) & 3);
        aoff[j] = (m0 + r) * DMODEL + c * 8;
        boff[j] = (n0 + r) * DMODEL + c * 8;
        loff[j] = p * 8;
    }

    int afrag[4], bfrag[4];
    {
        int rho = lane & 15, h = lane >> 4;
        #pragma unroll
        for (int mi = 0; mi < 4; mi++) {
            int r = wm + mi * 16 + rho;
            afrag[mi] = (4 * r + (h ^ ((r >> 1) & 3))) * 8;
            int rn = wn + mi * 16 + rho;
            bfrag[mi] = (4 * rn + (h ^ ((rn >> 1) & 3))) * 8;
        }
    }

    for (int k0 = 0; k0 < DMODEL; k0 += 64) {
        #pragma unroll
        for (int h = 0; h < 2; h++)
            #pragma unroll
            for (int j = 0; j < 2; j++) {
                async16(Xb + aoff[j] + k0 + h * 32, As[h] + loff[j]);
                async16(Wb + boff[j] + k0 + h * 32, Bs[h] + loff[j]);
            }
        __syncthreads();

        #pragma unroll
        for (int h = 0; h < 2; h++) {
            short8 af[4], bf[4];
            #pragma unroll
            for (int i = 0; i < 4; i++) {
                af[i] = *(const short8*)&As[h][afrag[i]];
                bf[i] = *(const short8*)&Bs[h][bfrag[i]];
            }
            #pragma unroll
            for (int mi = 0; mi < 4; mi++)
                #pragma unroll
                for (int ni = 0; ni < 4; ni++)
                    acc[mi][ni] = __builtin_amdgcn_mfma_f32_16x16x32_bf16(
                        af[mi], bf[ni], acc[mi][ni], 0, 0, 0);
        }
        __syncthreads();
    }

    // Epilogue: bias add, bf16 logit store, per-row (64-col) max1/max2/idx
    const int colb = n0 + wn + (lane & 15);
    const int rowb = m0 + wm + (lane >> 4) * 4;
    const int chunk = (n0 + wn) >> 6;   // 0..9
    float bv[4];
    #pragma unroll
    for (int ni = 0; ni < 4; ni++) bv[ni] = bias[colb + ni * 16];

    #pragma unroll
    for (int mi = 0; mi < 4; mi++) {
        #pragma unroll
        for (int p = 0; p < 4; p++) {
            const int row = rowb + mi * 16 + p;
            // local max over this lane's 4 cols (ascending col order)
            float m1 = acc[mi][0][p] + bv[0];
            float m2 = NEG_INF;
            int i1 = colb;
            logits[row * NOUT + colb] = f2bf(m1);
            #pragma unroll
            for (int ni = 1; ni < 4; ni++) {
                float v = acc[mi][ni][p] + bv[ni];
                logits[row * NOUT + colb + ni * 16] = f2bf(v);
                if (v > m1) { m2 = m1; m1 = v; i1 = colb + ni * 16; }
                else        { m2 = fmaxf(m2, v); }
            }
            // reduce across the 16 lanes of this row group (xor 1,2,4,8)
            #pragma unroll
            for (int off = 1; off < 16; off <<= 1) {
                float om1 = __shfl_xor(m1, off);
                float om2 = __shfl_xor(m2, off);
                int   oi  = __shfl_xor(i1, off);
                float nm2 = fmaxf(fmaxf(m2, om2), fminf(m1, om1));
                if (om1 > m1 || (om1 == m1 && oi < i1)) { m1 = om1; i1 = oi; }
                m2 = nm2;
            }
            if ((lane & 15) == 0) {
                rec_m1[row * NCHUNK + chunk] = m1;
                rec_m2[row * NCHUNK + chunk] = m2;
                rec_id[row * NCHUNK + chunk] = i1;
            }
        }
    }
}

// ---------------------------------------------------------------------------
// Kernel 3: FUSED reduce + resolve + gather. NO fences/hist/done (per-block
// device-scope fences measured catastrophic twice: r3 +130us, r9 +90us).
// r11: 1024 blocks x 32 pairs (16 tokens) — doubles block-level parallelism,
// halves phase-2 straggler impact; phase 3 is the r4-proven 16-token gather.
// ---------------------------------------------------------------------------
__global__ __launch_bounds__(256) void finalize_kernel(
    const float* __restrict__ X, const float* __restrict__ W,
    const float* __restrict__ bias,
    const unsigned short* __restrict__ logits,
    const float* __restrict__ rec_m1, const float* __restrict__ rec_m2,
    const int* __restrict__ rec_id,
    const float* __restrict__ cb,
    float* __restrict__ out, float* __restrict__ out_idx)
{
    __shared__ int   lcol[32];    // global codebook row per local pair
    __shared__ float lM[32];      // chunk-max for ambiguous pairs
    __shared__ int   lamb[32];    // compacted local indices of ambiguous pairs
    __shared__ int   slcnt;

    const int tid   = threadIdx.x;
    const int lane  = tid & 63;
    const int wave  = tid >> 6;
    const int pair0 = blockIdx.x * 32;

    // ---- phase 1: reduce (lanes 0..31 of wave 0; lane == local pair) ----
    if (tid < 32) {
        const int pair  = pair0 + tid;
        const int token = pair >> 1;
        const int g     = pair & 1;
        const int base  = token * NCHUNK + g * 5;

        float m1[5], M;
        int cstar = 0;
        #pragma unroll
        for (int c = 0; c < 5; c++) m1[c] = rec_m1[base + c];
        M = m1[0];
        #pragma unroll
        for (int c = 1; c < 5; c++)
            if (m1[c] > M) { M = m1[c]; cstar = c; }
        const float m2s = rec_m2[base + cstar];

        const float thr = M - MARGIN;
        bool amb = (m2s >= thr);
        #pragma unroll
        for (int c = 0; c < 5; c++)
            if (c != cstar && m1[c] >= thr) amb = true;

        if (!amb) {
            const int gcol = rec_id[base + cstar];       // global col
            lcol[tid] = gcol;
            out_idx[pair] = (float)(gcol - g * VOCAB);
        } else {
            lM[tid] = M;
        }
        unsigned long long mask = __ballot(amb);   // bits 32..63 are 0
        if (amb) {
            int off = __popcll(mask & ((1ull << tid) - 1ull));
            lamb[off] = tid;
        }
        if (tid == 0) slcnt = (int)__popcll(mask);
    }
    __syncthreads();
    const int nloc = slcnt;

    // ---- phase 2: resolve ambiguous (wave-per-slot over LDS list) ----
    for (int s = wave; s < nloc; s += 4) {
        const int lp    = lamb[s];
        const int pair  = pair0 + lp;
        const float M   = lM[lp];
        const int token = pair >> 1;
        const int g     = pair & 1;

        // cache this token's X row: 16 floats per lane
        const float4* xr = (const float4*)(X + (size_t)token * DMODEL);
        float4 xv[4];
        #pragma unroll
        for (int q = 0; q < 4; q++) xv[q] = xr[lane + 64 * q];

        // load this pair's bf16 logit row (40 lanes x 8 values = 320)
        const unsigned short* lp_ = logits + token * NOUT + g * VOCAB;
        const bool have = (lane < 40);
        ushort8 u = (ushort8)0;
        if (have) u = *(const ushort8*)(lp_ + lane * 8);

        const float thr = M - MARGIN;
        float best = NEG_INF;
        int bestcol = 0;

        #pragma unroll
        for (int j = 0; j < 8; j++) {
            bool c = have && (bf2f(u[j]) >= thr);
            unsigned long long mask = __ballot(c);   // wave-uniform
            while (mask) {
                const int b = __ffsll((long long)mask) - 1;
                mask &= mask - 1;
                const int col = b * 8 + j;           // 0..319
                const float4* wr = (const float4*)(W + (size_t)(g * VOCAB + col) * DMODEL);
                float acc = 0.0f;
                #pragma unroll
                for (int q = 0; q < 4; q++) {
                    float4 bb = wr[lane + 64 * q];
                    acc = fmaf(xv[q].x, bb.x, acc);
                    acc = fmaf(xv[q].y, bb.y, acc);
                    acc = fmaf(xv[q].z, bb.z, acc);
                    acc = fmaf(xv[q].w, bb.w, acc);
                }
                #pragma unroll
                for (int off = 32; off >= 1; off >>= 1)
                    acc += __shfl_xor(acc, off);
                const float logit = acc + bias[g * VOCAB + col];
                if (logit > best || (logit == best && col < bestcol)) {
                    best = logit; bestcol = col;
                }
            }
        }
        if (lane == 0) {
            lcol[lp] = g * VOCAB + bestcol;
            out_idx[pair] = (float)bestcol;
        }
    }
    __syncthreads();

    // ---- phase 3: gather 16 tokens x 1024 floats (one row per iter) ----
    #pragma unroll 4
    for (int i = 0; i < 16; i++) {
        const int token = pair0 / 2 + i;
        const int gg = tid >> 7;
        const float4* src = (const float4*)(cb + (size_t)lcol[i * 2 + gg] * DG);
        ((float4*)(out + (size_t)token * DMODEL))[tid] = src[tid & 127];
    }
}

// ---------------------------------------------------------------------------
// Kernel 4: diversity loss — single block builds the histogram from out_idx
// in LDS (LDS atomics) and computes the scalar. 128 KB read, trivial.
// ---------------------------------------------------------------------------
__global__ __launch_bounds__(256) void diversity_kernel(
    const float* __restrict__ out_idx, float* __restrict__ out_scalar)
{
    __shared__ int lhist[NOUT];
    __shared__ float s0[256], s1[256];
    const int tid = threadIdx.x;
    for (int i = tid; i < NOUT; i += 256) lhist[i] = 0;
    __syncthreads();

    // NPAIR = 32768 floats; read as float4 (pairs 4i..4i+3, g = pair&1)
    const float4* oi4 = (const float4*)out_idx;
    for (int i = tid; i < NPAIR / 4; i += 256) {
        float4 v = oi4[i];
        atomicAdd(&lhist[0 * VOCAB + (int)v.x], 1);   // pair 4i   : g=0
        atomicAdd(&lhist[1 * VOCAB + (int)v.y], 1);   // pair 4i+1 : g=1
        atomicAdd(&lhist[0 * VOCAB + (int)v.z], 1);   // pair 4i+2 : g=0
        atomicAdd(&lhist[1 * VOCAB + (int)v.w], 1);   // pair 4i+3 : g=1
    }
    __syncthreads();

    float a0 = 0.0f, a1 = 0.0f;
    for (int i = tid; i < NOUT; i += 256) {
        float m = (float)lhist[i] * (1.0f / (float)NTOK);
        float t = m * logf(m + 1e-7f);
        if (i < VOCAB) a0 += t; else a1 += t;
    }
    s0[tid] = a0; s1[tid] = a1;
    __syncthreads();
    for (int s = 128; s > 0; s >>= 1) {
        if (tid < s) { s0[tid] += s0[tid + s]; s1[tid] += s1[tid + s]; }
        __syncthreads();
    }
    if (tid == 0) {
        float perplexity = expf(-s0[0]) + expf(-s1[0]);
        *out_scalar = ((float)NOUT - perplexity) / (float)NOUT * 0.1f;
    }
}

// ---------------------------------------------------------------------------
extern "C" void kernel_launch(void* const* d_in, const int* in_sizes, int n_in,
                              void* d_out, int out_size, void* d_ws, size_t ws_size,
                              hipStream_t stream) {
    const float* X    = (const float*)d_in[0];
    const float* W    = (const float*)d_in[1];
    const float* bias = (const float*)d_in[2];
    const float* cb   = (const float*)d_in[3];

    float* out      = (float*)d_out;
    float* out_idx  = out + (size_t)NTOK * DMODEL;
    float* out_loss = out_idx + NPAIR;

    // workspace layout
    char* p = (char*)d_ws;
    unsigned short* Xb = (unsigned short*)p;      p += (size_t)NTOK * DMODEL * 2;   // 32 MB
    unsigned short* Wb = (unsigned short*)p;      p += (size_t)NOUT * DMODEL * 2;   // 1.25 MB
    unsigned short* logits = (unsigned short*)p;  p += (size_t)NTOK * NOUT * 2;     // 20 MB
    float* rec_m1 = (float*)p;                    p += (size_t)NTOK * NCHUNK * 4;   // 640 KB
    float* rec_m2 = (float*)p;                    p += (size_t)NTOK * NCHUNK * 4;
    int*   rec_id = (int*)p;                      p += (size_t)NTOK * NCHUNK * 4;

    convert_kernel<<<(NX8 + NW8 + 255) / 256, 256, 0, stream>>>(X, W, Xb, Wb);

    // 1-D grid, XCD-chunked swizzle inside the kernel (640 = 8 XCDs x 80)
    gemm_bf16_kernel<<<640, 256, 0, stream>>>(Xb, Wb, bias, logits,
                                              rec_m1, rec_m2, rec_id);

    finalize_kernel<<<NPAIR / 32, 256, 0, stream>>>(X, W, bias, logits,
                                                    rec_m1, rec_m2, rec_id,
                                                    cb, out, out_idx);

    diversity_kernel<<<1, 256, 0, stream>>>(out_idx, out_loss);
}